// Round 7
// baseline (249.766 us; speedup 1.0000x reference)
//
#include <hip/hip_runtime.h>

#define N_SEQ 2048
#define S_LEN 4096
#define W_SEQ 64                               // u64 words per sequence (S/64)
#define TILE 64                                // 64x64 pair tile
#define T_TILES (N_SEQ / TILE)                 // 32
#define NTILE (T_TILES * (T_TILES + 1) / 2)    // 528 upper-triangle tiles
#define KSPLIT 4
#define NBLK (NTILE * KSPLIT)                  // 2112 pair blocks (~8.25/CU)
#define KWORDS (W_SEQ / KSPLIT)                // 16 words per block
#define CHUNK 8                                // words per LDS K-chunk
#define LSTRIDE 9                              // u128 per LDS row (8 + 1 pad)
#define NSITES (N_SEQ * S_LEN)                 // 8388608
#define ENC_BLOCKS 4096
#define ENC_THREADS (ENC_BLOCKS * 256)         // 1048576 -> 8 sites/thread

typedef float vfloat4 __attribute__((ext_vector_type(4)));

// ---------------- Kernel 1: encode + zprep (unchanged, proven) ----------------
__global__ __launch_bounds__(256) void encode_kernel(const vfloat4* __restrict__ data,
                                                     const float* __restrict__ table,
                                                     ulonglong2* __restrict__ codes,
                                                     float4* __restrict__ zbuf) {
    int tid = threadIdx.x;
    int gtid = blockIdx.x * 256 + tid;

    if (gtid < N_SEQ) {
        float vx = table[2 * gtid], vy = table[2 * gtid + 1];
        float n = sqrtf(vx * vx + vy * vy);
        float f = tanhf(n) / fmaxf(n, 1e-12f);
        float zx = vx * f, zy = vy * f;
        zbuf[gtid] = make_float4(zx, zy, 1.0f - (zx * zx + zy * zy), 0.0f);
    }

#pragma unroll
    for (int it = 0; it < NSITES / ENC_THREADS; ++it) {
        int t = gtid + it * ENC_THREADS;
        vfloat4 v = __builtin_nontemporal_load(&data[t]);   // read-once 134 MB stream
        unsigned long long lo = __ballot(v.y + v.w > 0.5f); // tokens 1,3
        unsigned long long hi = __ballot(v.z + v.w > 0.5f); // tokens 2,3
        if ((tid & 63) == 0) {
            ulonglong2 e; e.x = lo; e.y = hi;
            codes[t >> 6] = e;
        }
    }
}

// ---------------- Kernel 2: popcount partial-hamming ----------------
// The R3-R6 synthesis: pairs is LDS-PIPE-bound (per-CU pipe shared by 4 SIMDs).
//  - 4x4 pairs/thread -> 0.5 ds_read_b128 per combo-word (halves R3's pipe load)
//  - KSPLIT=4 -> 2112 blocks (~8.25/CU, balanced; fixes R0's 528-block tail)
//  - CHUNK=8 -> LDS 18.4 KB -> 8 blocks/CU co-resident
//  - __launch_bounds__(256,8) -> compiler must fit <=64 VGPR -> 32 waves/CU
//    (R4/R6 lesson: dropping below ~32 waves/CU exposes staging latency and
//     costs more than the LDS-traffic win; R5 lesson: no reg arrays across
//     barriers -> b-fragment is read ONE at a time inside the l-loop)
// Floor: 1.08M wave ds_read_b128 x 12cyc / 256CU ~ 21 us.
__global__ __launch_bounds__(256, 8) void pairs_kernel(const ulonglong2* __restrict__ codes,
                                                       unsigned short* __restrict__ misbuf) {
    __shared__ ulonglong2 As[TILE * LSTRIDE];   // 64*9*16 = 9216 B
    __shared__ ulonglong2 Bs[TILE * LSTRIDE];   // total 18432 B

    int bid = blockIdx.x;
    int tb = bid >> 2, ko = bid & 3;           // tile index, K-quarter
    // triangle mapping: tb = r*(r+1)/2 + c, c <= r (i-tile = c, j-tile = r)
    int r = (int)((sqrtf(8.0f * (float)tb + 1.0f) - 1.0f) * 0.5f);
    while ((r + 1) * (r + 2) / 2 <= tb) ++r;
    while (r * (r + 1) / 2 > tb) --r;
    int c = tb - r * (r + 1) / 2;
    int i0 = c * TILE, j0 = r * TILE;
    int w0 = ko * KWORDS;

    int tid = threadIdx.x;
    int tx = tid & 15, ty = tid >> 4;          // 16x16 thread grid

    // staging: per chunk 64 rows x 8 words, 2 cells/thread/buffer.
    // row = tid>>3 + 32p, w = tid&7  -> all 32 banks active on ds_write_b128
    // (row stride 9 u128 = 36 dwords -> bank = 4*((row+w) mod 8)).
    int srow = tid >> 3, sw = tid & 7;
    const ulonglong2* gA = codes + (size_t)(i0 + srow) * W_SEQ + w0 + sw;
    const ulonglong2* gB = codes + (size_t)(j0 + srow) * W_SEQ + w0 + sw;
    ulonglong2* lA = As + srow * LSTRIDE + sw;
    ulonglong2* lB = Bs + srow * LSTRIDE + sw;

    int mis[4][4];
#pragma unroll
    for (int k = 0; k < 4; ++k)
#pragma unroll
        for (int l = 0; l < 4; ++l) mis[k][l] = 0;

    for (int cc = 0; cc < KWORDS / CHUNK; ++cc) {    // 2 chunks
#pragma unroll
        for (int p = 0; p < 2; ++p) {                // rows +32 per pass
            lA[p * 32 * LSTRIDE] = gA[(size_t)(p * 32) * W_SEQ + cc * CHUNK];
            lB[p * 32 * LSTRIDE] = gB[(size_t)(p * 32) * W_SEQ + cc * CHUNK];
        }
        __syncthreads();
#pragma unroll
        for (int w = 0; w < CHUNK; ++w) {
            ulonglong2 a[4];
#pragma unroll
            for (int k = 0; k < 4; ++k) a[k] = As[(ty + 16 * k) * LSTRIDE + w];
#pragma unroll
            for (int l = 0; l < 4; ++l) {
                ulonglong2 b = Bs[(tx + 16 * l) * LSTRIDE + w];   // one at a time: low VGPR
#pragma unroll
                for (int k = 0; k < 4; ++k)
                    mis[k][l] += __popcll((a[k].x ^ b.x) | (a[k].y ^ b.y));
            }
        }
        __syncthreads();
    }

    // write partial counts (max 1024, fits u16); slot private per block, no RMW
    unsigned short* mo = misbuf + (size_t)bid * (TILE * TILE);
#pragma unroll
    for (int k = 0; k < 4; ++k)
#pragma unroll
        for (int l = 0; l < 4; ++l)
            mo[(ty + 16 * k) * TILE + tx + 16 * l] = (unsigned short)mis[k][l];
}

// ---------------- Kernel 3: combine K-quarters + hyperbolic epilogue ----------------
// 528 blocks x 256 thr; thread owns 16 contiguous pairs of one tile row.
// Reads 4 partial planes as u32 (2 u16 each), totals, applies the nonlinear
// distance + weighted sq-diff, block-reduces to part[t]. ~17 MB traffic.
__global__ __launch_bounds__(256) void epi_kernel(const unsigned short* __restrict__ misbuf,
                                                  const float4* __restrict__ zbuf,
                                                  const float* __restrict__ log_scale,
                                                  double* __restrict__ part) {
    __shared__ float wsum[4];
    int t = blockIdx.x;
    int r = (int)((sqrtf(8.0f * (float)t + 1.0f) - 1.0f) * 0.5f);
    while ((r + 1) * (r + 2) / 2 <= t) ++r;
    while (r * (r + 1) / 2 > t) --r;
    int c = t - r * (r + 1) / 2;
    int i0 = c * TILE, j0 = r * TILE;

    int tid = threadIdx.x;
    int row = tid >> 2;                        // 0..63
    int c0  = (tid & 3) * 16;                  // 16 cols per thread

    // partial plane h for tile t lives at misbuf + (4t+h)*4096 u16
    const unsigned* m0 = (const unsigned*)(misbuf + (size_t)(4 * t) * (TILE * TILE)
                                           + row * TILE + c0);
    const unsigned* m1 = m0 + (TILE * TILE) / 2;   // u32 units: 2048
    const unsigned* m2 = m1 + (TILE * TILE) / 2;
    const unsigned* m3 = m2 + (TILE * TILE) / 2;

    float scale = expf(log_scale[0]);
    const float inv_s = 1.0f / (float)S_LEN;
    int i = i0 + row;
    float4 zi = zbuf[i];
    float local = 0.0f;
#pragma unroll
    for (int q = 0; q < 8; ++q) {              // 8 u32 = 16 u16 cols
        unsigned u0 = m0[q], u1 = m1[q], u2 = m2[q], u3 = m3[q];
#pragma unroll
        for (int h = 0; h < 2; ++h) {
            int mtot = (int)((u0 >> (16 * h)) & 0xffffu) + (int)((u1 >> (16 * h)) & 0xffffu)
                     + (int)((u2 >> (16 * h)) & 0xffffu) + (int)((u3 >> (16 * h)) & 0xffffu);
            int j = j0 + c0 + 2 * q + h;
            float4 zj = zbuf[j];
            float ham = (float)mtot * inv_s;
            float dx = zi.x - zj.x, dy = zi.y - zj.y;
            float dsq = dx * dx + dy * dy;
            float arg = 1.0f + 2.0f * dsq / (zi.z * zj.z);
            arg = fmaxf(arg, 1.0f + 1e-7f);
            float dist = acoshf(arg) * scale;
            float d = ham - dist;
            float wgt = (i < j) ? 2.0f : (i == j ? 1.0f : 0.0f);
            local += wgt * d * d;
        }
    }

#pragma unroll
    for (int off = 32; off > 0; off >>= 1) local += __shfl_down(local, off);
    if ((tid & 63) == 0) wsum[tid >> 6] = local;
    __syncthreads();
    if (tid == 0)
        part[t] = (double)(wsum[0] + wsum[1] + wsum[2] + wsum[3]);
}

// ---------------- Kernel 4: tiny deterministic final reduce ----------------
__global__ __launch_bounds__(256) void reduce_kernel(const double* __restrict__ part,
                                                     float* __restrict__ out) {
    __shared__ double ws[4];
    int tid = threadIdx.x;
    double s = 0.0;
    for (int i = tid; i < NTILE; i += 256) s += part[i];
#pragma unroll
    for (int off = 32; off > 0; off >>= 1) s += __shfl_down(s, off);
    if ((tid & 63) == 0) ws[tid >> 6] = s;
    __syncthreads();
    if (tid == 0)
        out[0] = (float)((ws[0] + ws[1] + ws[2] + ws[3]) /
                         ((double)N_SEQ * (double)N_SEQ));
}

extern "C" void kernel_launch(void* const* d_in, const int* in_sizes, int n_in,
                              void* d_out, int out_size, void* d_ws, size_t ws_size,
                              hipStream_t stream) {
    const vfloat4* data     = (const vfloat4*)d_in[0]; // N x S x A fp32 one-hot
    const float*  table     = (const float*)d_in[1];   // N x 2
    const float*  log_scale = (const float*)d_in[2];   // scalar
    float* out = (float*)d_out;

    // ws layout (poison fill proves ws >= 512 MB):
    char* ws = (char*)d_ws;
    ulonglong2*     codes  = (ulonglong2*)ws;                                    // 2 MB
    float4*         zbuf   = (float4*)(ws + (size_t)N_SEQ * W_SEQ * sizeof(ulonglong2));
    unsigned short* misbuf = (unsigned short*)((char*)zbuf + (size_t)N_SEQ * sizeof(float4));
    double*         part   = (double*)((char*)misbuf +
                                       (size_t)NBLK * TILE * TILE * sizeof(unsigned short)); // +17.3 MB

    encode_kernel<<<ENC_BLOCKS, 256, 0, stream>>>(data, table, codes, zbuf);
    pairs_kernel <<<NBLK,       256, 0, stream>>>(codes, misbuf);
    epi_kernel   <<<NTILE,      256, 0, stream>>>(misbuf, zbuf, log_scale, part);
    reduce_kernel<<<1,          256, 0, stream>>>(part, out);
}

// Round 8
// 230.393 us; speedup vs baseline: 1.0841x; 1.0841x over previous
//
#include <hip/hip_runtime.h>

#define N_SEQ 2048
#define S_LEN 4096
#define W_SEQ 64                               // u64 words per sequence (S/64)
#define TILE 32                                // finer tiles: better CU load balance
#define T_TILES (N_SEQ / TILE)                 // 64
#define NBLK (T_TILES * (T_TILES + 1) / 2)     // 2080 upper-triangle tiles (~8.1/CU)
#define CHUNK 16                               // words per LDS K-chunk
#define STRIDE 17                              // padded LDS row stride (conflict-free)
#define NSITES (N_SEQ * S_LEN)                 // 8388608
#define ENC_BLOCKS 4096
#define ENC_THREADS (ENC_BLOCKS * 256)         // 1048576 -> 8 sites/thread

typedef float vfloat4 __attribute__((ext_vector_type(4)));   // native vec for nontemporal builtin

// ---------------- Kernel 1: encode + zprep ----------------
// one-hot fp32 -> 2-bit packed bit-planes (wave __ballot), plus tiny z-prep.
// HBM-stream-bound: 134 MB read-once at ~6.5 TB/s => ~21-25 us floor.
__global__ __launch_bounds__(256) void encode_kernel(const vfloat4* __restrict__ data,
                                                     const float* __restrict__ table,
                                                     ulonglong2* __restrict__ codes,
                                                     float4* __restrict__ zbuf) {
    int tid = threadIdx.x;
    int gtid = blockIdx.x * 256 + tid;

    if (gtid < N_SEQ) {
        float vx = table[2 * gtid], vy = table[2 * gtid + 1];
        float n = sqrtf(vx * vx + vy * vy);
        float f = tanhf(n) / fmaxf(n, 1e-12f);
        float zx = vx * f, zy = vy * f;
        float omn = 1.0f - (zx * zx + zy * zy);      // 1 - ||z||^2
        zbuf[gtid] = make_float4(zx, zy, omn, 0.0f);
    }

    // grid-stride; stride is a multiple of 64 so each wave maps to one u64 word.
    // tokens: 0->x, 1->y, 2->z, 3->w  =>  lo-plane = y|w, hi-plane = z|w.
#pragma unroll
    for (int it = 0; it < NSITES / ENC_THREADS; ++it) {
        int t = gtid + it * ENC_THREADS;
        vfloat4 v = __builtin_nontemporal_load(&data[t]);   // read-once 134 MB stream
        unsigned long long lo = __ballot(v.y + v.w > 0.5f);
        unsigned long long hi = __ballot(v.z + v.w > 0.5f);
        if ((tid & 63) == 0) {
            ulonglong2 e; e.x = lo; e.y = hi;
            codes[t >> 6] = e;
        }
    }
}

// ---------------- Kernel 2: pairwise popcount-hamming + hyperbolic ----
// 32x32 pair tile per block; 16x16 threads, each owns 2x2 pairs. 2080 blocks
// (~8.1/CU) balance the CUs; high residency hides staging latency via TLP.
// R4-R7 sweep: every config that halves LDS reads/combo (bigger reg tile /
// K-split) loses more to staging-barrier overhead or occupancy — this point
// is the measured optimum of the LDS-staged popcount structure.
// ATOMIC-FREE epilogue (R2 lesson: cross-XCD sync is poison): partial per
// block to part[bid]; kernel boundary orders it for the reduce.
__global__ __launch_bounds__(256, 4) void pairs_kernel(const ulonglong2* __restrict__ codes,
                                                       const float4* __restrict__ zbuf,
                                                       const float* __restrict__ log_scale,
                                                       double* __restrict__ part) {
    __shared__ ulonglong2 As[TILE * STRIDE];
    __shared__ ulonglong2 Bs[TILE * STRIDE];
    __shared__ float wsum[4];

    int bid = blockIdx.x;
    // triangle mapping: bid = r*(r+1)/2 + c, c <= r (i-tile = c, j-tile = r)
    int r = (int)((sqrtf(8.0f * (float)bid + 1.0f) - 1.0f) * 0.5f);
    while ((r + 1) * (r + 2) / 2 <= bid) ++r;
    while (r * (r + 1) / 2 > bid) --r;
    int c = bid - r * (r + 1) / 2;
    int i0 = c * TILE, j0 = r * TILE;

    int tid = threadIdx.x;
    int tx = tid & 15, ty = tid >> 4;

    // staging: entry e = tid + p*256 -> row = e>>4 (0..31), word = e&15
    int srow = tid >> 4, sw = tid & 15;
    const ulonglong2* gA = codes + (size_t)(i0 + srow) * W_SEQ + sw;
    const ulonglong2* gB = codes + (size_t)(j0 + srow) * W_SEQ + sw;
    ulonglong2* lA = As + srow * STRIDE + sw;
    ulonglong2* lB = Bs + srow * STRIDE + sw;

    int mis[2][2];
#pragma unroll
    for (int k = 0; k < 2; ++k)
#pragma unroll
        for (int l = 0; l < 2; ++l) mis[k][l] = 0;

    for (int cc = 0; cc < W_SEQ / CHUNK; ++cc) {
#pragma unroll
        for (int p = 0; p < 2; ++p) {              // +16 rows per pass, 32 rows total
            lA[p * 16 * STRIDE] = gA[(size_t)(p * 16) * W_SEQ + cc * CHUNK];
            lB[p * 16 * STRIDE] = gB[(size_t)(p * 16) * W_SEQ + cc * CHUNK];
        }
        __syncthreads();
#pragma unroll
        for (int w = 0; w < CHUNK; ++w) {
            ulonglong2 a[2], bb[2];
#pragma unroll
            for (int k = 0; k < 2; ++k) a[k] = As[(ty + 16 * k) * STRIDE + w];
#pragma unroll
            for (int l = 0; l < 2; ++l) bb[l] = Bs[(tx + 16 * l) * STRIDE + w];
#pragma unroll
            for (int k = 0; k < 2; ++k)
#pragma unroll
                for (int l = 0; l < 2; ++l)
                    mis[k][l] += __popcll((a[k].x ^ bb[l].x) | (a[k].y ^ bb[l].y));
        }
        __syncthreads();
    }

    // fused epilogue: exact hamming, hyperbolic dist, symmetry-weighted sq-diff
    float scale = expf(log_scale[0]);
    const float inv_s = 1.0f / (float)S_LEN;
    float local = 0.0f;
#pragma unroll
    for (int k = 0; k < 2; ++k) {
        int i = i0 + ty + 16 * k;
        float4 zi = zbuf[i];
#pragma unroll
        for (int l = 0; l < 2; ++l) {
            int j = j0 + tx + 16 * l;
            float4 zj = zbuf[j];
            float ham = (float)mis[k][l] * inv_s;
            float dx = zi.x - zj.x, dy = zi.y - zj.y;
            float dsq = dx * dx + dy * dy;
            float arg = 1.0f + 2.0f * dsq / (zi.z * zj.z);
            arg = fmaxf(arg, 1.0f + 1e-7f);
            float dist = acoshf(arg) * scale;
            float d = ham - dist;
            float wgt = (i < j) ? 2.0f : (i == j ? 1.0f : 0.0f);
            local += wgt * d * d;
        }
    }

#pragma unroll
    for (int off = 32; off > 0; off >>= 1) local += __shfl_down(local, off);
    if ((tid & 63) == 0) wsum[tid >> 6] = local;
    __syncthreads();

    if (tid == 0)
        part[bid] = (double)(wsum[0] + wsum[1] + wsum[2] + wsum[3]);  // private slot, no RMW
}

// ---------------- Kernel 3: tiny deterministic final reduce ----------------
// 1 block, 64 lanes; sums 2080 doubles (~33 loads/lane). Few us incl. launch.
__global__ __launch_bounds__(64) void reduce_kernel(const double* __restrict__ part,
                                                    float* __restrict__ out) {
    double s = 0.0;
    for (int i = threadIdx.x; i < NBLK; i += 64) s += part[i];
#pragma unroll
    for (int off = 32; off > 0; off >>= 1) s += __shfl_down(s, off);
    if (threadIdx.x == 0)
        out[0] = (float)(s / ((double)N_SEQ * (double)N_SEQ));
}

extern "C" void kernel_launch(void* const* d_in, const int* in_sizes, int n_in,
                              void* d_out, int out_size, void* d_ws, size_t ws_size,
                              hipStream_t stream) {
    const vfloat4* data     = (const vfloat4*)d_in[0]; // N x S x A fp32 one-hot
    const float*  table     = (const float*)d_in[1];   // N x 2
    const float*  log_scale = (const float*)d_in[2];   // scalar
    float* out = (float*)d_out;

    char* ws = (char*)d_ws;
    ulonglong2* codes   = (ulonglong2*)ws;                                       // 2 MB
    float4*     zbuf    = (float4*)(ws + (size_t)N_SEQ * W_SEQ * sizeof(ulonglong2));
    double*     part    = (double*)((char*)zbuf + (size_t)N_SEQ * sizeof(float4));

    encode_kernel<<<ENC_BLOCKS, 256, 0, stream>>>(data, table, codes, zbuf);
    pairs_kernel <<<NBLK,       256, 0, stream>>>(codes, zbuf, log_scale, part);
    reduce_kernel<<<1,          64,  0, stream>>>(part, out);
}